// Round 1
// baseline (836.083 us; speedup 1.0000x reference)
//
#include <hip/hip_runtime.h>
#include <hip/hip_bf16.h>

typedef unsigned short u16;
typedef unsigned int   u32;

using bf16x8 = __attribute__((ext_vector_type(8))) short;  // 8 bf16 (4 VGPRs)
using f32x4  = __attribute__((ext_vector_type(4))) float;  // MFMA accum
using fvec4  = __attribute__((ext_vector_type(4))) float;
using u16x4  = __attribute__((ext_vector_type(4))) unsigned short;

#define BSZ   8192
#define DIN   2048
#define MMD   1600
#define NCH   20
#define CSZ   80
#define DOUT  3000

// ---------- bf16 helpers (raw-bits, no API-name dependence) ----------
__device__ __forceinline__ float bf2f(u16 u) {
    u32 x = ((u32)u) << 16; float f; __builtin_memcpy(&f, &x, 4); return f;
}
__device__ __forceinline__ u16 f2bf(float f) {  // RNE
    u32 x; __builtin_memcpy(&x, &f, 4);
    u32 r = x + 0x7fffu + ((x >> 16) & 1u);
    return (u16)(r >> 16);
}

// ---------- async global->LDS, 16B per lane, wave-uniform LDS base ----------
__device__ __forceinline__ void gl2lds16(const void* g, const void* l) {
    __builtin_amdgcn_global_load_lds(
        (const __attribute__((address_space(1))) u32*)g,
        (__attribute__((address_space(3))) u32*)l, 16, 0, 0);
}

// ---------- converters ----------
__global__ void cast_bf16_k(const float* __restrict__ src, u16* __restrict__ dst, int n4) {
    int i = blockIdx.x * blockDim.x + threadIdx.x;
    if (i < n4) {
        fvec4 v = ((const fvec4*)src)[i];
        u16x4 o;
        o.x = f2bf(v.x); o.y = f2bf(v.y); o.z = f2bf(v.z); o.w = f2bf(v.w);
        ((u16x4*)dst)[i] = o;
    }
}

// src: [K][N] f32 row-major -> dst: [Npad][K] bf16 row-major, zero for n>=N.
// grid = (K/32, Npad/32), block = 256
__global__ void transpose_cast_k(const float* __restrict__ src, u16* __restrict__ dst,
                                 int K, int N) {
    __shared__ float t[32][33];
    int k0 = blockIdx.x * 32, n0 = blockIdx.y * 32;
    int tx = threadIdx.x & 31, ty = threadIdx.x >> 5;  // ty in [0,8)
#pragma unroll
    for (int r = 0; r < 4; r++) {
        int n = n0 + tx;
        float v = (n < N) ? src[(size_t)(k0 + ty + 8 * r) * N + n] : 0.f;
        t[ty + 8 * r][tx] = v;
    }
    __syncthreads();
#pragma unroll
    for (int r = 0; r < 4; r++)
        dst[(size_t)(n0 + ty + 8 * r) * K + k0 + tx] = f2bf(t[tx][ty + 8 * r]);
}

// ---------- m97-style GEMM: C[M][N] = A[M][K] @ BT[N][K]^T + bias ----------
// A,BT bf16; BT padded to gridDim.y*128 rows (zeros). 128x128 tile, BK=64.
template<bool OUT_BF16>
__global__ __launch_bounds__(256, 2) void gemm_bt_k(
    const u16* __restrict__ A, const u16* __restrict__ BT,
    const float* __restrict__ bias, void* __restrict__ C, int K, int N) {
    __shared__ __align__(16) u16 As[128 * 64];
    __shared__ __align__(16) u16 Bs[128 * 64];
    const int tid = threadIdx.x, w = tid >> 6, lane = tid & 63;
    const int lr = lane & 15, lk = lane >> 4;
    const int m0 = blockIdx.x * 128, n0 = blockIdx.y * 128;
    const int mh = (w >> 1) * 64, nh = (w & 1) * 64;
    f32x4 acc[4][4] = {};
    const u16* Ag = A + (size_t)m0 * K;
    const u16* Bg = BT + (size_t)n0 * K;
    const int nslab = K >> 6;
    for (int kt = 0; kt < nslab; ++kt) {
        const int k0 = kt * 64;
        __syncthreads();
#pragma unroll
        for (int q = 0; q < 4; q++) {
            int ch = w * 4 + q;
            int L = ch * 64 + lane;
            int row = L >> 3, off = L & 7;
            gl2lds16(Ag + (size_t)row * K + k0 + off * 8, As + ch * 512);
            gl2lds16(Bg + (size_t)row * K + k0 + off * 8, Bs + ch * 512);
        }
        __syncthreads();
#pragma unroll
        for (int ks = 0; ks < 64; ks += 32) {
            bf16x8 av[4], bv[4];
#pragma unroll
            for (int i = 0; i < 4; i++)
                av[i] = *(const bf16x8*)(As + (mh + i * 16 + lr) * 64 + ks + lk * 8);
#pragma unroll
            for (int j = 0; j < 4; j++)
                bv[j] = *(const bf16x8*)(Bs + (nh + j * 16 + lr) * 64 + ks + lk * 8);
#pragma unroll
            for (int i = 0; i < 4; i++)
#pragma unroll
                for (int j = 0; j < 4; j++)
                    acc[i][j] = __builtin_amdgcn_mfma_f32_16x16x32_bf16(av[i], bv[j], acc[i][j], 0, 0, 0);
        }
    }
    // epilogue: C/D layout col=lane&15, row=(lane>>4)*4+reg  [m89-verified]
#pragma unroll
    for (int j = 0; j < 4; j++) {
        int n = n0 + nh + j * 16 + lr;
        if (n < N) {
            float bv = bias[n];
#pragma unroll
            for (int i = 0; i < 4; i++) {
                int mb = m0 + mh + i * 16 + lk * 4;
#pragma unroll
                for (int r = 0; r < 4; r++) {
                    float v = acc[i][j][r] + bv;
                    if (OUT_BF16) ((u16*)C)[(size_t)(mb + r) * N + n] = f2bf(v);
                    else          ((float*)C)[(size_t)(mb + r) * N + n] = v;
                }
            }
        }
    }
}

// ---------- fused bilinear + signed-sqrt + per-chunk L2 norm ----------
// grid = (64 m-tiles, 20 chunks), block=256. Per chunk: z = Aouter @ Wb[c]^T(flat),
// Aouter[b, s*80+t] = h0c[b,s]*h1c[b,t] generated straight into A-fragments.
__global__ __launch_bounds__(256, 2) void bilinear_k(
    const u16* __restrict__ h0g, const u16* __restrict__ h1g,
    const u16* __restrict__ Wbg, const float* __restrict__ bbg,
    u16* __restrict__ zg) {
    __shared__ __align__(16) u16 h0s[128 * CSZ];
    __shared__ __align__(16) u16 h1s[128 * CSZ];
    __shared__ __align__(16) u16 Ws[CSZ * 64];
    const int tid = threadIdx.x, w = tid >> 6, lane = tid & 63;
    const int lr = lane & 15, lk = lane >> 4;
    const int m0 = blockIdx.x * 128, c = blockIdx.y;
    const u16* g0 = h0g + (size_t)m0 * MMD + c * CSZ;
    const u16* g1 = h1g + (size_t)m0 * MMD + c * CSZ;
    // stage h0/h1 chunk tiles [128][80] once (20 x 1KB chunks each, 5 per wave)
#pragma unroll
    for (int q = 0; q < 5; q++) {
        int ch = w * 5 + q;
        int L = ch * 64 + lane;      // 16B units; 160B rows = 10 units
        int row = L / 10, off = L - row * 10;
        gl2lds16(g0 + (size_t)row * MMD + off * 8, h0s + ch * 512);
        gl2lds16(g1 + (size_t)row * MMD + off * 8, h1s + ch * 512);
    }
    f32x4 acc[2][5] = {};
    const u16* Wg = Wbg + (size_t)c * CSZ * 6400;
    for (int kt = 0; kt < 100; ++kt) {
        const int k0 = kt * 64;
        __syncthreads();
        for (int ch = w; ch < 10; ch += 4) {  // Wb slab [80][64]: 10 x 1KB
            int L = ch * 64 + lane;
            int row = L >> 3, off = L & 7;
            gl2lds16(Wg + (size_t)row * 6400 + k0 + off * 8, Ws + ch * 512);
        }
        __syncthreads();
#pragma unroll
        for (int ks = 0; ks < 64; ks += 32) {
            bf16x8 bv[5];
#pragma unroll
            for (int j = 0; j < 5; j++)
                bv[j] = *(const bf16x8*)(Ws + (j * 16 + lr) * 64 + ks + lk * 8);
            int kg = k0 + ks + lk * 8;   // 8-aligned, 80%8==0 -> single s per octet
            int s = kg / 80;
            int t0 = kg - s * 80;
            bf16x8 av[2];
#pragma unroll
            for (int i = 0; i < 2; i++) {
                int m = w * 32 + i * 16 + lr;
                union { u16 u; __hip_bfloat16 h; } cu;
                cu.u = h0s[m * CSZ + s];
                __hip_bfloat162 h00; h00.x = cu.h; h00.y = cu.h;
                union { bf16x8 v; __hip_bfloat162 b2[4]; } hv, pv;
                hv.v = *(const bf16x8*)(h1s + m * CSZ + t0);
#pragma unroll
                for (int p = 0; p < 4; p++) pv.b2[p] = __hmul2(h00, hv.b2[p]);
                av[i] = pv.v;
            }
#pragma unroll
            for (int i = 0; i < 2; i++)
#pragma unroll
                for (int j = 0; j < 5; j++)
                    acc[i][j] = __builtin_amdgcn_mfma_f32_16x16x32_bf16(av[i], bv[j], acc[i][j], 0, 0, 0);
        }
    }
    // epilogue: +bb, signed sqrt, L2-normalize each row over the 80 chunk cols
    float bbv[5];
#pragma unroll
    for (int j = 0; j < 5; j++) bbv[j] = bbg[c * CSZ + j * 16 + lr];
    float sq[2][4] = {};
#pragma unroll
    for (int i = 0; i < 2; i++)
#pragma unroll
        for (int j = 0; j < 5; j++)
#pragma unroll
            for (int r = 0; r < 4; r++) {
                float v = acc[i][j][r] + bbv[j];
                float a = sqrtf(fabsf(v));
                v = (v < 0.f) ? -a : a;
                acc[i][j][r] = v;
                sq[i][r] += v * v;
            }
#pragma unroll
    for (int d = 1; d < 16; d <<= 1)
#pragma unroll
        for (int i = 0; i < 2; i++)
#pragma unroll
            for (int r = 0; r < 4; r++)
                sq[i][r] += __shfl_xor(sq[i][r], d, 64);
    float sc[2][4];
#pragma unroll
    for (int i = 0; i < 2; i++)
#pragma unroll
        for (int r = 0; r < 4; r++)
            sc[i][r] = 1.f / fmaxf(sqrtf(sq[i][r]), 1e-12f);
#pragma unroll
    for (int i = 0; i < 2; i++)
#pragma unroll
        for (int r = 0; r < 4; r++) {
            int row = m0 + w * 32 + i * 16 + lk * 4 + r;
#pragma unroll
            for (int j = 0; j < 5; j++) {
                int col = c * CSZ + j * 16 + lr;
                zg[(size_t)row * MMD + col] = f2bf(acc[i][j][r] * sc[i][r]);
            }
        }
}

// ---------- launcher ----------
extern "C" void kernel_launch(void* const* d_in, const int* in_sizes, int n_in,
                              void* d_out, int out_size, void* d_ws, size_t ws_size,
                              hipStream_t stream) {
    (void)in_sizes; (void)n_in; (void)out_size; (void)ws_size;
    const float* x0 = (const float*)d_in[0];
    const float* x1 = (const float*)d_in[1];
    const float* W0 = (const float*)d_in[2];
    const float* b0 = (const float*)d_in[3];
    const float* W1 = (const float*)d_in[4];
    const float* b1 = (const float*)d_in[5];
    const float* Wb = (const float*)d_in[6];
    const float* bb = (const float*)d_in[7];
    const float* Wo = (const float*)d_in[8];
    const float* bo = (const float*)d_in[9];

    char* ws = (char*)d_ws;
    size_t off = 0;
    auto alloc = [&](size_t bytes) { void* p = ws + off; off += (bytes + 255) & ~(size_t)255; return p; };
    u16* x0b = (u16*)alloc((size_t)BSZ * DIN * 2);       // 33.5 MB
    u16* x1b = (u16*)alloc((size_t)BSZ * DIN * 2);       // 33.5 MB
    u16* W0T = (u16*)alloc((size_t)1664 * DIN * 2);      // 6.8 MB  (N padded 1600->1664)
    u16* W1T = (u16*)alloc((size_t)1664 * DIN * 2);      // 6.8 MB
    u16* WbB = (u16*)alloc((size_t)NCH * CSZ * 6400 * 2);// 20.5 MB (straight cast)
    u16* WoT = (u16*)alloc((size_t)3072 * MMD * 2);      // 9.8 MB  (N padded 3000->3072)
    u16* h0  = (u16*)alloc((size_t)BSZ * MMD * 2);       // 26.2 MB
    u16* h1  = (u16*)alloc((size_t)BSZ * MMD * 2);       // 26.2 MB
    u16* z   = x0b;  // alias: x0b dead after first GEMM  (total ws ~164 MB)

    // converters
    cast_bf16_k<<<dim3(16384), dim3(256), 0, stream>>>(x0, x0b, (BSZ * DIN) / 4);
    cast_bf16_k<<<dim3(16384), dim3(256), 0, stream>>>(x1, x1b, (BSZ * DIN) / 4);
    cast_bf16_k<<<dim3(10000), dim3(256), 0, stream>>>(Wb, WbB, (NCH * CSZ * 6400) / 4);
    transpose_cast_k<<<dim3(DIN / 32, 1664 / 32), dim3(256), 0, stream>>>(W0, W0T, DIN, MMD);
    transpose_cast_k<<<dim3(DIN / 32, 1664 / 32), dim3(256), 0, stream>>>(W1, W1T, DIN, MMD);
    transpose_cast_k<<<dim3(MMD / 32, 3072 / 32), dim3(256), 0, stream>>>(Wo, WoT, MMD, DOUT);
    // projections -> h0,h1 (bf16)
    gemm_bt_k<true><<<dim3(BSZ / 128, 13), dim3(256), 0, stream>>>(x0b, W0T, b0, h0, DIN, MMD);
    gemm_bt_k<true><<<dim3(BSZ / 128, 13), dim3(256), 0, stream>>>(x1b, W1T, b1, h1, DIN, MMD);
    // fused bilinear + signed sqrt + chunk L2 norm -> z (bf16)
    bilinear_k<<<dim3(BSZ / 128, NCH), dim3(256), 0, stream>>>(h0, h1, WbB, bb, z);
    // final projection -> out (f32)
    gemm_bt_k<false><<<dim3(BSZ / 128, 24), dim3(256), 0, stream>>>(z, WoT, bo, d_out, MMD, DOUT);
}

// Round 2
// 748.870 us; speedup vs baseline: 1.1165x; 1.1165x over previous
//
#include <hip/hip_runtime.h>
#include <hip/hip_bf16.h>

typedef unsigned short u16;
typedef unsigned int   u32;

using bf16x8 = __attribute__((ext_vector_type(8))) short;  // 8 bf16 (4 VGPRs)
using f32x4  = __attribute__((ext_vector_type(4))) float;  // MFMA accum
using fvec4  = __attribute__((ext_vector_type(4))) float;
using u16x4  = __attribute__((ext_vector_type(4))) unsigned short;

#define BSZ   8192
#define DIN   2048
#define MMD   1600
#define NCH   20
#define CSZ   80
#define DOUT  3000

// ---------- bf16 helpers ----------
__device__ __forceinline__ float bf2f(u16 u) {
    u32 x = ((u32)u) << 16; float f; __builtin_memcpy(&f, &x, 4); return f;
}
__device__ __forceinline__ u16 f2bf(float f) {  // RNE
    u32 x; __builtin_memcpy(&x, &f, 4);
    u32 r = x + 0x7fffu + ((x >> 16) & 1u);
    return (u16)(r >> 16);
}
// broadcast-scalar * packed bf16 pair -> packed bf16 pair (truncating pack).
// 5 VALU: shl, and, 2x mul, v_perm. Trunc bias is a uniform scale per chunk
// row -> cancelled by the L2 normalization.
__device__ __forceinline__ u32 bmul2(float h, u32 pair) {
    u32 ulo = pair << 16, uhi = pair & 0xffff0000u;
    float flo, fhi;
    __builtin_memcpy(&flo, &ulo, 4); __builtin_memcpy(&fhi, &uhi, 4);
    float plo = h * flo, phi = h * fhi;
    u32 a, b;
    __builtin_memcpy(&a, &plo, 4); __builtin_memcpy(&b, &phi, 4);
    return __builtin_amdgcn_perm(b, a, 0x07060302u);
}

// ---------- async global->LDS, 16B/lane, wave-uniform LDS base ----------
__device__ __forceinline__ void gl2lds16(const void* g, const void* l) {
    __builtin_amdgcn_global_load_lds(
        (const __attribute__((address_space(1))) u32*)g,
        (__attribute__((address_space(3))) u32*)l, 16, 0, 0);
}

// ---------- converters ----------
__global__ void cast_bf16_k(const float* __restrict__ src, u16* __restrict__ dst, int n4) {
    int i = blockIdx.x * blockDim.x + threadIdx.x;
    if (i < n4) {
        fvec4 v = ((const fvec4*)src)[i];
        u16x4 o;
        o.x = f2bf(v.x); o.y = f2bf(v.y); o.z = f2bf(v.z); o.w = f2bf(v.w);
        ((u16x4*)dst)[i] = o;
    }
}

// src: [K][N] f32 -> dst: [Npad][K] bf16, zero rows for n>=N.
__global__ void transpose_cast_k(const float* __restrict__ src, u16* __restrict__ dst,
                                 int K, int N) {
    __shared__ float t[32][33];
    int k0 = blockIdx.x * 32, n0 = blockIdx.y * 32;
    int tx = threadIdx.x & 31, ty = threadIdx.x >> 5;
#pragma unroll
    for (int r = 0; r < 4; r++) {
        int n = n0 + tx;
        float v = (n < N) ? src[(size_t)(k0 + ty + 8 * r) * N + n] : 0.f;
        t[ty + 8 * r][tx] = v;
    }
    __syncthreads();
#pragma unroll
    for (int r = 0; r < 4; r++)
        dst[(size_t)(n0 + ty + 8 * r) * K + k0 + tx] = f2bf(t[tx][ty + 8 * r]);
}

// ---------- m97-style GEMM with XOR-swizzled LDS (conflict fix) ----------
// LDS tile [128 rows][8 octets of 16B]: phys_oct = oct ^ (row & 7).
// Staging keeps global_load_lds by permuting the SOURCE address.
template<bool OUT_BF16>
__global__ __launch_bounds__(256, 2) void gemm_bt_k(
    const u16* __restrict__ A, const u16* __restrict__ BT,
    const float* __restrict__ bias, void* __restrict__ C, int K, int N) {
    __shared__ __align__(16) u16 As[128 * 64];
    __shared__ __align__(16) u16 Bs[128 * 64];
    const int tid = threadIdx.x, w = tid >> 6, lane = tid & 63;
    const int lr = lane & 15, lk = lane >> 4, s7 = lr & 7;
    const int m0 = blockIdx.x * 128, n0 = blockIdx.y * 128;
    const int mh = (w >> 1) * 64, nh = (w & 1) * 64;
    const int so = (lane & 7) ^ (lane >> 3);   // staging source-octet permute
    int arow[4], brow[4];
#pragma unroll
    for (int i = 0; i < 4; i++) { arow[i] = (mh + i * 16 + lr) * 64; brow[i] = (nh + i * 16 + lr) * 64; }
    f32x4 acc[4][4] = {};
    const u16* Ag = A + (size_t)m0 * K;
    const u16* Bg = BT + (size_t)n0 * K;
    const int nslab = K >> 6;
    for (int kt = 0; kt < nslab; ++kt) {
        const int k0 = kt * 64;
        __syncthreads();
#pragma unroll
        for (int q = 0; q < 4; q++) {
            int ch = w * 4 + q;
            int row = ch * 8 + (lane >> 3);      // row & 7 == lane>>3
            gl2lds16(Ag + (size_t)row * K + k0 + so * 8, As + ch * 512);
            gl2lds16(Bg + (size_t)row * K + k0 + so * 8, Bs + ch * 512);
        }
        __syncthreads();
#pragma unroll
        for (int ks = 0; ks < 64; ks += 32) {
            const int px = (((ks >> 3) + lk) ^ s7) * 8;
            bf16x8 av[4], bv[4];
#pragma unroll
            for (int i = 0; i < 4; i++) av[i] = *(const bf16x8*)(As + arow[i] + px);
#pragma unroll
            for (int j = 0; j < 4; j++) bv[j] = *(const bf16x8*)(Bs + brow[j] + px);
#pragma unroll
            for (int i = 0; i < 4; i++)
#pragma unroll
                for (int j = 0; j < 4; j++)
                    acc[i][j] = __builtin_amdgcn_mfma_f32_16x16x32_bf16(av[i], bv[j], acc[i][j], 0, 0, 0);
        }
    }
#pragma unroll
    for (int j = 0; j < 4; j++) {
        int n = n0 + nh + j * 16 + lr;
        if (n < N) {
            float bv = bias[n];
#pragma unroll
            for (int i = 0; i < 4; i++) {
                int mb = m0 + mh + i * 16 + lk * 4;
#pragma unroll
                for (int r = 0; r < 4; r++) {
                    float v = acc[i][j][r] + bv;
                    if (OUT_BF16) ((u16*)C)[(size_t)(mb + r) * N + n] = f2bf(v);
                    else          ((float*)C)[(size_t)(mb + r) * N + n] = v;
                }
            }
        }
    }
}

// ---------- fused bilinear + signed-sqrt + per-chunk L2 norm ----------
// h1s rotation-swizzled (10 octets/row): phys_oct = (oct + row) % 10.
// Ws XOR-swizzled like the GEMM. h0s identity (scalar reads only).
__global__ __launch_bounds__(256, 3) void bilinear_k(
    const u16* __restrict__ h0g, const u16* __restrict__ h1g,
    const u16* __restrict__ Wbg, const float* __restrict__ bbg,
    u16* __restrict__ zg) {
    __shared__ __align__(16) u16 h0s[128 * CSZ];
    __shared__ __align__(16) u16 h1s[128 * CSZ];
    __shared__ __align__(16) u16 Ws[CSZ * 64];
    const int tid = threadIdx.x, w = tid >> 6, lane = tid & 63;
    const int lr = lane & 15, lk = lane >> 4, s7 = lr & 7;
    const int m0 = blockIdx.x * 128, c = blockIdx.y;
    const u16* g0 = h0g + (size_t)m0 * MMD + c * CSZ;
    const u16* g1 = h1g + (size_t)m0 * MMD + c * CSZ;
    // one-time staging of h tiles; h1 source-permuted for rotation swizzle
#pragma unroll
    for (int q = 0; q < 5; q++) {
        int ch = w * 5 + q;
        int p = ch * 64 + lane;
        int row = p / 10, po = p - row * 10;
        int r10 = row - (row / 10) * 10;
        int o = po - r10; o += (o < 0) ? 10 : 0;
        gl2lds16(g0 + (size_t)row * MMD + po * 8, h0s + ch * 512);
        gl2lds16(g1 + (size_t)row * MMD + o * 8, h1s + ch * 512);
    }
    const int so = (lane & 7) ^ (lane >> 3);
    int mb80[2], mm10[2], wrow[5];
#pragma unroll
    for (int i = 0; i < 2; i++) {
        int m = w * 32 + i * 16 + lr;
        mb80[i] = m * CSZ;
        mm10[i] = m % 10;
    }
#pragma unroll
    for (int j = 0; j < 5; j++) wrow[j] = (j * 16 + lr) * 64;
    f32x4 acc[2][5] = {};
    const u16* Wg = Wbg + (size_t)c * CSZ * 6400;
    const int klk = lk * 8;
    for (int kt = 0; kt < 100; ++kt) {
        const int k0 = kt * 64;
        __syncthreads();
        for (int ch = w; ch < 10; ch += 4) {     // Wb slab [80][64]
            int row = ch * 8 + (lane >> 3);      // row & 7 == lane>>3
            gl2lds16(Wg + (size_t)row * 6400 + k0 + so * 8, Ws + ch * 512);
        }
        __syncthreads();
#pragma unroll
        for (int ks = 0; ks < 64; ks += 32) {
            const int px = (((ks >> 3) + lk) ^ s7) * 8;
            bf16x8 bv[5];
#pragma unroll
            for (int j = 0; j < 5; j++) bv[j] = *(const bf16x8*)(Ws + wrow[j] + px);
            int kg = k0 + ks + klk;              // 8-aligned; 80%8==0 -> fixed s
            int s = kg / 80;
            int ot = (kg - s * 80) >> 3;
            bf16x8 av[2];
#pragma unroll
            for (int i = 0; i < 2; i++) {
                float h0f = bf2f(h0s[mb80[i] + s]);
                int ph = ot + mm10[i]; ph = (ph < 10) ? ph : ph - 10;
                union { bf16x8 v; u32 u[4]; } hv, pv;
                hv.v = *(const bf16x8*)(h1s + mb80[i] + ph * 8);
#pragma unroll
                for (int p = 0; p < 4; p++) pv.u[p] = bmul2(h0f, hv.u[p]);
                av[i] = pv.v;
            }
#pragma unroll
            for (int i = 0; i < 2; i++)
#pragma unroll
                for (int j = 0; j < 5; j++)
                    acc[i][j] = __builtin_amdgcn_mfma_f32_16x16x32_bf16(av[i], bv[j], acc[i][j], 0, 0, 0);
        }
    }
    // epilogue: +bb, signed sqrt, per-row L2 norm over the 80 chunk cols
    float bbv[5];
#pragma unroll
    for (int j = 0; j < 5; j++) bbv[j] = bbg[c * CSZ + j * 16 + lr];
    float sq[2][4] = {};
#pragma unroll
    for (int i = 0; i < 2; i++)
#pragma unroll
        for (int j = 0; j < 5; j++)
#pragma unroll
            for (int r = 0; r < 4; r++) {
                float v = acc[i][j][r] + bbv[j];
                float a = sqrtf(fabsf(v));
                v = (v < 0.f) ? -a : a;
                acc[i][j][r] = v;
                sq[i][r] += v * v;
            }
#pragma unroll
    for (int d = 1; d < 16; d <<= 1)
#pragma unroll
        for (int i = 0; i < 2; i++)
#pragma unroll
            for (int r = 0; r < 4; r++)
                sq[i][r] += __shfl_xor(sq[i][r], d, 64);
    float sc[2][4];
#pragma unroll
    for (int i = 0; i < 2; i++)
#pragma unroll
        for (int r = 0; r < 4; r++)
            sc[i][r] = 1.f / fmaxf(sqrtf(sq[i][r]), 1e-12f);
#pragma unroll
    for (int i = 0; i < 2; i++)
#pragma unroll
        for (int r = 0; r < 4; r++) {
            int row = m0 + w * 32 + i * 16 + lk * 4 + r;
#pragma unroll
            for (int j = 0; j < 5; j++) {
                int col = c * CSZ + j * 16 + lr;
                zg[(size_t)row * MMD + col] = f2bf(acc[i][j][r] * sc[i][r]);
            }
        }
}

// ---------- launcher ----------
extern "C" void kernel_launch(void* const* d_in, const int* in_sizes, int n_in,
                              void* d_out, int out_size, void* d_ws, size_t ws_size,
                              hipStream_t stream) {
    (void)in_sizes; (void)n_in; (void)out_size; (void)ws_size;
    const float* x0 = (const float*)d_in[0];
    const float* x1 = (const float*)d_in[1];
    const float* W0 = (const float*)d_in[2];
    const float* b0 = (const float*)d_in[3];
    const float* W1 = (const float*)d_in[4];
    const float* b1 = (const float*)d_in[5];
    const float* Wb = (const float*)d_in[6];
    const float* bb = (const float*)d_in[7];
    const float* Wo = (const float*)d_in[8];
    const float* bo = (const float*)d_in[9];

    char* ws = (char*)d_ws;
    size_t off = 0;
    auto alloc = [&](size_t bytes) { void* p = ws + off; off += (bytes + 255) & ~(size_t)255; return p; };
    u16* x0b = (u16*)alloc((size_t)BSZ * DIN * 2);
    u16* x1b = (u16*)alloc((size_t)BSZ * DIN * 2);
    u16* W0T = (u16*)alloc((size_t)1664 * DIN * 2);
    u16* W1T = (u16*)alloc((size_t)1664 * DIN * 2);
    u16* WbB = (u16*)alloc((size_t)NCH * CSZ * 6400 * 2);
    u16* WoT = (u16*)alloc((size_t)3072 * MMD * 2);
    u16* h0  = (u16*)alloc((size_t)BSZ * MMD * 2);
    u16* h1  = (u16*)alloc((size_t)BSZ * MMD * 2);
    u16* z   = x0b;  // alias: x0b dead after first GEMM

    cast_bf16_k<<<dim3(16384), dim3(256), 0, stream>>>(x0, x0b, (BSZ * DIN) / 4);
    cast_bf16_k<<<dim3(16384), dim3(256), 0, stream>>>(x1, x1b, (BSZ * DIN) / 4);
    cast_bf16_k<<<dim3(10000), dim3(256), 0, stream>>>(Wb, WbB, (NCH * CSZ * 6400) / 4);
    transpose_cast_k<<<dim3(DIN / 32, 1664 / 32), dim3(256), 0, stream>>>(W0, W0T, DIN, MMD);
    transpose_cast_k<<<dim3(DIN / 32, 1664 / 32), dim3(256), 0, stream>>>(W1, W1T, DIN, MMD);
    transpose_cast_k<<<dim3(MMD / 32, 3072 / 32), dim3(256), 0, stream>>>(Wo, WoT, MMD, DOUT);
    gemm_bt_k<true><<<dim3(BSZ / 128, 13), dim3(256), 0, stream>>>(x0b, W0T, b0, h0, DIN, MMD);
    gemm_bt_k<true><<<dim3(BSZ / 128, 13), dim3(256), 0, stream>>>(x1b, W1T, b1, h1, DIN, MMD);
    bilinear_k<<<dim3(BSZ / 128, NCH), dim3(256), 0, stream>>>(h0, h1, WbB, bb, z);
    gemm_bt_k<false><<<dim3(BSZ / 128, 24), dim3(256), 0, stream>>>(z, WoT, bo, d_out, MMD, DOUT);
}

// Round 3
// 730.774 us; speedup vs baseline: 1.1441x; 1.0248x over previous
//
#include <hip/hip_runtime.h>
#include <hip/hip_bf16.h>

typedef unsigned short u16;
typedef unsigned int   u32;

using bf16x8 = __attribute__((ext_vector_type(8))) short;  // 8 bf16 (4 VGPRs)
using f32x4  = __attribute__((ext_vector_type(4))) float;  // MFMA accum
using fvec4  = __attribute__((ext_vector_type(4))) float;
using u16x4  = __attribute__((ext_vector_type(4))) unsigned short;

#define BSZ   8192
#define DIN   2048
#define MMD   1600
#define NCH   20
#define CSZ   80
#define DOUT  3000

// ---------- bf16 helpers ----------
__device__ __forceinline__ float bf2f(u16 u) {
    u32 x = ((u32)u) << 16; float f; __builtin_memcpy(&f, &x, 4); return f;
}
__device__ __forceinline__ u16 f2bf(float f) {  // RNE
    u32 x; __builtin_memcpy(&x, &f, 4);
    u32 r = x + 0x7fffu + ((x >> 16) & 1u);
    return (u16)(r >> 16);
}

// ---------- async global->LDS, 16B/lane, wave-uniform LDS base ----------
__device__ __forceinline__ void gl2lds16(const void* g, const void* l) {
    __builtin_amdgcn_global_load_lds(
        (const __attribute__((address_space(1))) u32*)g,
        (__attribute__((address_space(3))) u32*)l, 16, 0, 0);
}

// ---------- converters ----------
__global__ void cast_bf16_k(const float* __restrict__ src, u16* __restrict__ dst, int n4) {
    int i = blockIdx.x * blockDim.x + threadIdx.x;
    if (i < n4) {
        fvec4 v = ((const fvec4*)src)[i];
        u16x4 o;
        o.x = f2bf(v.x); o.y = f2bf(v.y); o.z = f2bf(v.z); o.w = f2bf(v.w);
        ((u16x4*)dst)[i] = o;
    }
}

// src: [K][N] f32 -> dst: [Npad][K] bf16, zero rows for n>=N.
__global__ void transpose_cast_k(const float* __restrict__ src, u16* __restrict__ dst,
                                 int K, int N) {
    __shared__ float t[32][33];
    int k0 = blockIdx.x * 32, n0 = blockIdx.y * 32;
    int tx = threadIdx.x & 31, ty = threadIdx.x >> 5;
#pragma unroll
    for (int r = 0; r < 4; r++) {
        int n = n0 + tx;
        float v = (n < N) ? src[(size_t)(k0 + ty + 8 * r) * N + n] : 0.f;
        t[ty + 8 * r][tx] = v;
    }
    __syncthreads();
#pragma unroll
    for (int r = 0; r < 4; r++)
        dst[(size_t)(n0 + ty + 8 * r) * K + k0 + tx] = f2bf(t[tx][ty + 8 * r]);
}

// ---------- m97-style GEMM with XOR-swizzled LDS (unchanged from R2) ----------
template<bool OUT_BF16>
__global__ __launch_bounds__(256, 2) void gemm_bt_k(
    const u16* __restrict__ A, const u16* __restrict__ BT,
    const float* __restrict__ bias, void* __restrict__ C, int K, int N) {
    __shared__ __align__(16) u16 As[128 * 64];
    __shared__ __align__(16) u16 Bs[128 * 64];
    const int tid = threadIdx.x, w = tid >> 6, lane = tid & 63;
    const int lr = lane & 15, lk = lane >> 4, s7 = lr & 7;
    const int m0 = blockIdx.x * 128, n0 = blockIdx.y * 128;
    const int mh = (w >> 1) * 64, nh = (w & 1) * 64;
    const int so = (lane & 7) ^ (lane >> 3);
    int arow[4], brow[4];
#pragma unroll
    for (int i = 0; i < 4; i++) { arow[i] = (mh + i * 16 + lr) * 64; brow[i] = (nh + i * 16 + lr) * 64; }
    f32x4 acc[4][4] = {};
    const u16* Ag = A + (size_t)m0 * K;
    const u16* Bg = BT + (size_t)n0 * K;
    const int nslab = K >> 6;
    for (int kt = 0; kt < nslab; ++kt) {
        const int k0 = kt * 64;
        __syncthreads();
#pragma unroll
        for (int q = 0; q < 4; q++) {
            int ch = w * 4 + q;
            int row = ch * 8 + (lane >> 3);
            gl2lds16(Ag + (size_t)row * K + k0 + so * 8, As + ch * 512);
            gl2lds16(Bg + (size_t)row * K + k0 + so * 8, Bs + ch * 512);
        }
        __syncthreads();
#pragma unroll
        for (int ks = 0; ks < 64; ks += 32) {
            const int px = (((ks >> 3) + lk) ^ s7) * 8;
            bf16x8 av[4], bv[4];
#pragma unroll
            for (int i = 0; i < 4; i++) av[i] = *(const bf16x8*)(As + arow[i] + px);
#pragma unroll
            for (int j = 0; j < 4; j++) bv[j] = *(const bf16x8*)(Bs + brow[j] + px);
#pragma unroll
            for (int i = 0; i < 4; i++)
#pragma unroll
                for (int j = 0; j < 4; j++)
                    acc[i][j] = __builtin_amdgcn_mfma_f32_16x16x32_bf16(av[i], bv[j], acc[i][j], 0, 0, 0);
        }
    }
#pragma unroll
    for (int j = 0; j < 4; j++) {
        int n = n0 + nh + j * 16 + lr;
        if (n < N) {
            float bv = bias[n];
#pragma unroll
            for (int i = 0; i < 4; i++) {
                int mb = m0 + mh + i * 16 + lk * 4;
#pragma unroll
                for (int r = 0; r < 4; r++) {
                    float v = acc[i][j][r] + bv;
                    if (OUT_BF16) ((u16*)C)[(size_t)(mb + r) * N + n] = f2bf(v);
                    else          ((float*)C)[(size_t)(mb + r) * N + n] = v;
                }
            }
        }
    }
}

// ---------- bilinear, restructured: z = sum_s h0[:,s] * (h1 @ Wb[c,:,s,:]^T) ----------
// Per s: P_s[m,n] = sum_t h1[m,t] Wb[c,n,s,t]  -- a pure bf16 GEMM, A = h1 (no
// on-the-fly products). Then z += h0[m,s] * P_s in f32 on C-layout registers.
// t padded 80->96 with zeros in LDS: 3x K32 MFMA per tile, conflict-neutral rows
// (96 u16 = 48 dw = 16 mod 32 banks), all LDS read addrs loop-invariant.
__global__ __launch_bounds__(256, 3) void bilinear_k(
    const u16* __restrict__ h0g, const u16* __restrict__ h1g,
    const u16* __restrict__ Wbg, const float* __restrict__ bbg,
    u16* __restrict__ zg) {
    __shared__ __align__(16) u16 h1s[128 * 96];   // 24576 B
    __shared__ __align__(16) u16 Ws[CSZ * 96];    // 15360 B (re-staged per s)
    const int tid = threadIdx.x, w = tid >> 6, lane = tid & 63;
    const int lr = lane & 15, lk = lane >> 4;
    const int m0 = blockIdx.x * 128, c = blockIdx.y;

    // one-time: stage h1 tile [128][80] into padded [128][96] rows (octet = 16B)
    const u16* g1 = h1g + (size_t)m0 * MMD + c * CSZ;
#pragma unroll
    for (int it = 0; it < 6; ++it) {
        int oct = it * 256 + tid;                 // 1536 octs total
        int row = oct / 12, o = oct - row * 12;
        if (o < 10)
            gl2lds16(g1 + (size_t)row * MMD + o * 8, h1s + (it * 256 + w * 64) * 8);
    }
    {   // zero pad octets (o = 10, 11): 256 octs, one 16B store per thread
        int oct = (tid >> 1) * 12 + 10 + (tid & 1);
        *(fvec4*)(h1s + oct * 8) = (fvec4){0.f, 0.f, 0.f, 0.f};
    }
    if (tid < 160) {  // Ws pad octets: 160, zeroed once (staging never touches them)
        int oct = (tid >> 1) * 12 + 10 + (tid & 1);
        *(fvec4*)(Ws + oct * 8) = (fvec4){0.f, 0.f, 0.f, 0.f};
    }

    // per-s Ws staging descriptors (960 real octs over 4 batches of 256)
    const u16* WgBase = Wbg + (size_t)c * CSZ * 6400;
    const u16* wsrc[4];
    bool wok[4];
    int wdst[4];
#pragma unroll
    for (int it = 0; it < 4; ++it) {
        int oct = it * 256 + tid;
        int row = oct / 12, o = oct - row * 12;
        wok[it] = (oct < 960) && (o < 10);
        wsrc[it] = WgBase + (size_t)row * 6400 + o * 8;  // advance +80 per s
        wdst[it] = (it * 256 + w * 64) * 8;
    }

    // loop-invariant LDS read offsets (u16 units); per-st step = +32 (imm)
    int aoff[2], boff[5];
#pragma unroll
    for (int i = 0; i < 2; ++i) aoff[i] = (w * 32 + i * 16 + lr) * 96 + lk * 8;
#pragma unroll
    for (int j = 0; j < 5; ++j) boff[j] = (j * 16 + lr) * 96 + lk * 8;

    // h0 scalars from global: uniform col pointer + per-lane row offsets (L1-hot)
    const u16* hbase = h0g + (size_t)m0 * MMD + c * CSZ;
    int hoff[8];
#pragma unroll
    for (int i = 0; i < 2; ++i)
#pragma unroll
        for (int r = 0; r < 4; ++r)
            hoff[i * 4 + r] = (w * 32 + i * 16 + lk * 4 + r) * MMD;

    f32x4 z[2][5] = {};
    const f32x4 zf = {0.f, 0.f, 0.f, 0.f};

    for (int s = 0; s < 80; ++s) {
        __syncthreads();                       // prior Ws readers done
#pragma unroll
        for (int it = 0; it < 4; ++it) {
            if (wok[it]) gl2lds16(wsrc[it], Ws + wdst[it]);
            wsrc[it] += CSZ;
        }
        u16 h0r[8];
        const u16* hs = hbase + s;
#pragma unroll
        for (int k = 0; k < 8; ++k) h0r[k] = hs[hoff[k]];
        __syncthreads();                       // staging visible (vmcnt drained)
        f32x4 P[2][5];
#pragma unroll
        for (int st = 0; st < 3; ++st) {
            bf16x8 av[2], bv[5];
#pragma unroll
            for (int i = 0; i < 2; ++i) av[i] = *(const bf16x8*)(h1s + aoff[i] + st * 32);
#pragma unroll
            for (int j = 0; j < 5; ++j) bv[j] = *(const bf16x8*)(Ws + boff[j] + st * 32);
#pragma unroll
            for (int i = 0; i < 2; ++i)
#pragma unroll
                for (int j = 0; j < 5; ++j)
                    P[i][j] = __builtin_amdgcn_mfma_f32_16x16x32_bf16(
                        av[i], bv[j], st == 0 ? zf : P[i][j], 0, 0, 0);
        }
#pragma unroll
        for (int i = 0; i < 2; ++i)
#pragma unroll
            for (int r = 0; r < 4; ++r) {
                float h0f = bf2f(h0r[i * 4 + r]);
#pragma unroll
                for (int j = 0; j < 5; ++j)
                    z[i][j][r] += h0f * P[i][j][r];
            }
    }

    // epilogue: +bb, signed sqrt, per-row L2 norm over the 80 chunk cols
    float bbv[5];
#pragma unroll
    for (int j = 0; j < 5; j++) bbv[j] = bbg[c * CSZ + j * 16 + lr];
    float sq[2][4] = {};
#pragma unroll
    for (int i = 0; i < 2; i++)
#pragma unroll
        for (int j = 0; j < 5; j++)
#pragma unroll
            for (int r = 0; r < 4; r++) {
                float v = z[i][j][r] + bbv[j];
                float a = sqrtf(fabsf(v));
                v = (v < 0.f) ? -a : a;
                z[i][j][r] = v;
                sq[i][r] += v * v;
            }
#pragma unroll
    for (int d = 1; d < 16; d <<= 1)
#pragma unroll
        for (int i = 0; i < 2; i++)
#pragma unroll
            for (int r = 0; r < 4; r++)
                sq[i][r] += __shfl_xor(sq[i][r], d, 64);
    float sc[2][4];
#pragma unroll
    for (int i = 0; i < 2; i++)
#pragma unroll
        for (int r = 0; r < 4; r++)
            sc[i][r] = 1.f / fmaxf(sqrtf(sq[i][r]), 1e-12f);
#pragma unroll
    for (int i = 0; i < 2; i++)
#pragma unroll
        for (int r = 0; r < 4; r++) {
            int row = m0 + w * 32 + i * 16 + lk * 4 + r;
#pragma unroll
            for (int j = 0; j < 5; j++) {
                int col = c * CSZ + j * 16 + lr;
                zg[(size_t)row * MMD + col] = f2bf(z[i][j][r] * sc[i][r]);
            }
        }
}

// ---------- launcher ----------
extern "C" void kernel_launch(void* const* d_in, const int* in_sizes, int n_in,
                              void* d_out, int out_size, void* d_ws, size_t ws_size,
                              hipStream_t stream) {
    (void)in_sizes; (void)n_in; (void)out_size; (void)ws_size;
    const float* x0 = (const float*)d_in[0];
    const float* x1 = (const float*)d_in[1];
    const float* W0 = (const float*)d_in[2];
    const float* b0 = (const float*)d_in[3];
    const float* W1 = (const float*)d_in[4];
    const float* b1 = (const float*)d_in[5];
    const float* Wb = (const float*)d_in[6];
    const float* bb = (const float*)d_in[7];
    const float* Wo = (const float*)d_in[8];
    const float* bo = (const float*)d_in[9];

    char* ws = (char*)d_ws;
    size_t off = 0;
    auto alloc = [&](size_t bytes) { void* p = ws + off; off += (bytes + 255) & ~(size_t)255; return p; };
    u16* x0b = (u16*)alloc((size_t)BSZ * DIN * 2);
    u16* x1b = (u16*)alloc((size_t)BSZ * DIN * 2);
    u16* W0T = (u16*)alloc((size_t)1664 * DIN * 2);
    u16* W1T = (u16*)alloc((size_t)1664 * DIN * 2);
    u16* WbB = (u16*)alloc((size_t)NCH * CSZ * 6400 * 2);
    u16* WoT = (u16*)alloc((size_t)3072 * MMD * 2);
    u16* h0  = (u16*)alloc((size_t)BSZ * MMD * 2);
    u16* h1  = (u16*)alloc((size_t)BSZ * MMD * 2);
    u16* z   = x0b;  // alias: x0b dead after first GEMM

    cast_bf16_k<<<dim3(16384), dim3(256), 0, stream>>>(x0, x0b, (BSZ * DIN) / 4);
    cast_bf16_k<<<dim3(16384), dim3(256), 0, stream>>>(x1, x1b, (BSZ * DIN) / 4);
    cast_bf16_k<<<dim3(10000), dim3(256), 0, stream>>>(Wb, WbB, (NCH * CSZ * 6400) / 4);
    transpose_cast_k<<<dim3(DIN / 32, 1664 / 32), dim3(256), 0, stream>>>(W0, W0T, DIN, MMD);
    transpose_cast_k<<<dim3(DIN / 32, 1664 / 32), dim3(256), 0, stream>>>(W1, W1T, DIN, MMD);
    transpose_cast_k<<<dim3(MMD / 32, 3072 / 32), dim3(256), 0, stream>>>(Wo, WoT, MMD, DOUT);
    gemm_bt_k<true><<<dim3(BSZ / 128, 13), dim3(256), 0, stream>>>(x0b, W0T, b0, h0, DIN, MMD);
    gemm_bt_k<true><<<dim3(BSZ / 128, 13), dim3(256), 0, stream>>>(x1b, W1T, b1, h1, DIN, MMD);
    bilinear_k<<<dim3(BSZ / 128, NCH), dim3(256), 0, stream>>>(h0, h1, WbB, bb, z);
    gemm_bt_k<false><<<dim3(BSZ / 128, 24), dim3(256), 0, stream>>>(z, WoT, bo, d_out, MMD, DOUT);
}